// Round 9
// baseline (578.887 us; speedup 1.0000x reference)
//
#include <hip/hip_runtime.h>
#include <stdint.h>

// LSTM2Encoder: x=emb[ids]; h0=lstm0(x); h1=lstm1(h0); out=relu(h1@Wlin^T+b)
// R11: full vocab-domain pipeline. Zero LSTM state => out[t]=F(emb[ids[t]]),
// so compute G = relu(H1 @ WL^T + b) over the 50432-row vocab table too
// (0.77x FLOPs, contiguous A), then out[t] = (f32)G[ids[t]] as a pure
// gather-copy. Cross-round ledger: gather INSIDE a GEMM's staging cost
// ~+100us (R7 residual 155 vs R8-R10 247-275) -- scattered 64B gl2lds
// chunks serialize VMEM in the sync-heavy K-loop. The gather-copy instead
// reads contiguous 1KB L3-hot rows and writes coalesced 134MB.
// G stored fp16 (51.6MB, dead H0f slot): adds <=9.8e-4 only for |out|>2
// (12-sigma improbable); total err ~1e-3 < 2e-3 threshold.
// prep and gemm<0> (147us each, dbuf+vmcnt(3), MfmaUtil 33%) unchanged.

typedef _Float16 half8 __attribute__((ext_vector_type(8)));
typedef __attribute__((ext_vector_type(4))) float float4v;
typedef __attribute__((ext_vector_type(4))) unsigned int uint4v;

__device__ __forceinline__ float sigmoidf_(float x) { return 1.0f / (1.0f + __expf(-x)); }
__device__ __forceinline__ float tanhf_(float x) { return 1.0f - 2.0f / (__expf(2.0f * x) + 1.0f); }

__device__ __forceinline__ void gl2lds16(const void* g, void* l) {
  __builtin_amdgcn_global_load_lds(
      (const __attribute__((address_space(1))) void*)g,
      (__attribute__((address_space(3))) void*)l, 16, 0, 0);
}

// ---------------- prep: emb->fp16; weights permuted+cast; biases folded ----
// W'[4j+g][k] = W[g*512+j][k]  (g in {i,f,g,o});  b'[4j+g] = b_ih[n]+b_hh[n]
// Also zeroes Ef pad rows [50257,50432) so pad outputs stay finite.
__global__ __launch_bounds__(256) void prep_kernel(
    const float* __restrict__ emb,
    const float* __restrict__ W0, const float* __restrict__ bi0, const float* __restrict__ bh0,
    const float* __restrict__ W1, const float* __restrict__ bi1, const float* __restrict__ bh1,
    const float* __restrict__ WL,
    _Float16* __restrict__ Ef,
    _Float16* __restrict__ W0f, _Float16* __restrict__ W1f, _Float16* __restrict__ WLf,
    float* __restrict__ b0p, float* __restrict__ b1p)
{
  int id = blockIdx.x * 256 + threadIdx.x;
  if (id < 3216448) {                               // emb cast (50257*512/8)
    const float* s = emb + (size_t)id * 8;
    float4v v0 = *(const float4v*)s;
    float4v v1 = *(const float4v*)(s + 4);
    union { _Float16 h[8]; uint4v u; } P;
#pragma unroll
    for (int e = 0; e < 4; ++e) { P.h[e] = (_Float16)v0[e]; P.h[4 + e] = (_Float16)v1[e]; }
    *(uint4v*)(Ef + (size_t)id * 8) = P.u;
  } else if (id < 3347520) {                        // W0 permute+cast (2048*512/8)
    int u = id - 3216448;
    int np = u >> 6, k0 = (u & 63) << 3;
    int n = ((np & 3) << 9) | (np >> 2);
    const float* s = W0 + n * 512 + k0;
    float4v v0 = *(const float4v*)s;
    float4v v1 = *(const float4v*)(s + 4);
    union { _Float16 h[8]; uint4v u; } P;
#pragma unroll
    for (int e = 0; e < 4; ++e) { P.h[e] = (_Float16)v0[e]; P.h[4 + e] = (_Float16)v1[e]; }
    *(uint4v*)(W0f + np * 512 + k0) = P.u;
  } else if (id < 3478592) {                        // W1
    int u = id - 3347520;
    int np = u >> 6, k0 = (u & 63) << 3;
    int n = ((np & 3) << 9) | (np >> 2);
    const float* s = W1 + n * 512 + k0;
    float4v v0 = *(const float4v*)s;
    float4v v1 = *(const float4v*)(s + 4);
    union { _Float16 h[8]; uint4v u; } P;
#pragma unroll
    for (int e = 0; e < 4; ++e) { P.h[e] = (_Float16)v0[e]; P.h[4 + e] = (_Float16)v1[e]; }
    *(uint4v*)(W1f + np * 512 + k0) = P.u;
  } else if (id < 3511360) {                        // WL straight cast (512*512/8)
    int u = id - 3478592;
    const float* s = WL + (size_t)u * 8;
    float4v v0 = *(const float4v*)s;
    float4v v1 = *(const float4v*)(s + 4);
    union { _Float16 h[8]; uint4v u8; } P;
#pragma unroll
    for (int e = 0; e < 4; ++e) { P.h[e] = (_Float16)v0[e]; P.h[4 + e] = (_Float16)v1[e]; }
    *(uint4v*)(WLf + (size_t)u * 8) = P.u8;
  } else if (id < 3513408) {                        // b0 fold+permute
    int np = id - 3511360;
    int n = ((np & 3) << 9) | (np >> 2);
    b0p[np] = bi0[n] + bh0[n];
  } else if (id < 3515456) {                        // b1
    int np = id - 3513408;
    int n = ((np & 3) << 9) | (np >> 2);
    b1p[np] = bi1[n] + bh1[n];
  } else if (id < 3526656) {                        // zero Ef pad rows (175x512)
    int u = id - 3515456;
    *(uint4v*)(Ef + 25731584 + (size_t)u * 8) = (uint4v){0u, 0u, 0u, 0u};
  }
}

// ---------------- vocab-domain GEMM, 256x128 tile, BK=32, dbuf K-loop ------
// 8 waves as 4x2 grid of 64x64 wave tiles. acc[i][j] = mfma(b[j], a[i], acc)
// -> acc rows = B-row index (gates for MODE 0), cols = vocab rows.
// MODE 0: LSTM layer  -> h = sig(o)*tanh(sig(i)*tanh(g)), write h fp16
// MODE 1: final linear -> g = relu(acc + bias), write fp16 (8B stores)
template <int MODE>
__global__ __launch_bounds__(512, 4) void gemm_kernel(
    const _Float16* __restrict__ A, const int* __restrict__ ids,
    const _Float16* __restrict__ B, const float* __restrict__ bias,
    _Float16* __restrict__ Of, float* __restrict__ Out,
    int nbShift, int nbMask)
{
  __shared__ __align__(16) char smem[65536];        // 2 x (16KB A + 8KB B); hT 20KB
  const int T = threadIdx.x;
  const int lane = T & 63;
  const int wv = T >> 6;
  const int wrow = wv >> 1, wcol = wv & 1;          // 4 x 2 wave grid
  // XCD-bijective swizzle -- only when grid % 8 == 0 (else identity)
  const int nwg = (int)gridDim.x;
  const int bid = (int)blockIdx.x;
  const int swz = ((nwg & 7) == 0) ? (bid & 7) * (nwg >> 3) + (bid >> 3) : bid;
  const int mb = swz >> nbShift;
  const int nb = swz & nbMask;
  const size_t t0 = (size_t)mb * 256;
  const int n0 = nb * 128;

  const int r0 = T >> 2;                            // 0..127
  const int qg = (T & 3) ^ ((r0 >> 1) & 3);
  size_t sr0 = t0 + r0, sr1 = t0 + 128 + r0;
  if (ids) { sr0 = (size_t)(unsigned)ids[sr0]; sr1 = (size_t)(unsigned)ids[sr1]; }
  const _Float16* gA0 = A + sr0 * 512 + qg * 8;
  const _Float16* gA1 = A + sr1 * 512 + qg * 8;
  const _Float16* gB  = B + (size_t)(n0 + r0) * 512 + qg * 8;

  const int d0 = T * 16;                            // byte offset within buffer
#define STAGE(dst) do { \
    gl2lds16(gA0, (dst) + d0); \
    gl2lds16(gA1, (dst) + 8192 + d0); \
    gl2lds16(gB,  (dst) + 16384 + d0); \
    gA0 += 32; gA1 += 32; gB += 32; } while (0)

  const int m_ = lane & 15, qf = lane >> 4;
  const int qs = qf ^ ((m_ >> 1) & 3);
  const int offA = wrow * 2048 + m_ * 32 + qs * 8;
  const int offB = 8192 + wcol * 2048 + m_ * 32 + qs * 8;

  float4v acc[4][4];
#pragma unroll
  for (int i = 0; i < 4; ++i)
#pragma unroll
    for (int j = 0; j < 4; ++j)
      acc[i][j] = (float4v){0.f, 0.f, 0.f, 0.f};

  char* bufc = smem;
  char* bufn = smem + 32768;
  STAGE(bufc);

  for (int it = 0; it < 16; ++it) {
    if (it < 15) {
      STAGE(bufn);                                  // prefetch next K-tile
      asm volatile("s_waitcnt vmcnt(3)" ::: "memory");  // cur landed; nxt in flight
    } else {
      asm volatile("s_waitcnt vmcnt(0)" ::: "memory");
    }
    __builtin_amdgcn_sched_barrier(0);
    __builtin_amdgcn_s_barrier();                   // all waves' cur visible

    const _Float16* cur = (const _Float16*)bufc;
    half8 a[4], b[4];
#pragma unroll
    for (int i = 0; i < 4; ++i) {
      a[i] = *(const half8*)(cur + offA + i * 512);
      b[i] = *(const half8*)(cur + offB + i * 512);
    }
#pragma unroll
    for (int i = 0; i < 4; ++i)
#pragma unroll
      for (int j = 0; j < 4; ++j)
        acc[i][j] = __builtin_amdgcn_mfma_f32_16x16x32_f16(b[j], a[i], acc[i][j], 0, 0, 0);
    __builtin_amdgcn_sched_barrier(0);
    __builtin_amdgcn_s_barrier();
    __builtin_amdgcn_sched_barrier(0);
    char* tc = bufc; bufc = bufn; bufn = tc;
  }
#undef STAGE

  float4v bq[4];
#pragma unroll
  for (int j = 0; j < 4; ++j)
    bq[j] = *(const float4v*)(bias + n0 + wcol * 64 + j * 16 + qf * 4);

  if (MODE == 0) {
    _Float16* hT = (_Float16*)smem;                 // 256 x 40 halfs (80B rows)
    const int ub = wcol * 16 + qf;                  // + j*4 -> unit col 0..31
#pragma unroll
    for (int i = 0; i < 4; ++i) {
      const int trow = wrow * 64 + i * 16 + m_;
#pragma unroll
      for (int j = 0; j < 4; ++j) {
        // regs = gates {i,f,g,o} of unit (ub+j*4); f unused (c_prev=0)
        float yi = acc[i][j][0] + bq[j][0];
        float yg = acc[i][j][2] + bq[j][2];
        float yo = acc[i][j][3] + bq[j][3];
        float cc = sigmoidf_(yi) * tanhf_(yg);
        float hh = sigmoidf_(yo) * tanhf_(cc);
        hT[trow * 40 + ub + j * 4] = (_Float16)hh;
      }
    }
    __syncthreads();
    const int tl = T >> 1, hf = T & 1;
    const _Float16* src = hT + tl * 40 + hf * 16;
    uint4v v0 = *(const uint4v*)(src);
    uint4v v1 = *(const uint4v*)(src + 8);
    _Float16* dst = Of + (t0 + tl) * 512 + (size_t)(nb * 32) + hf * 16;
    *(uint4v*)dst = v0;
    *(uint4v*)(dst + 8) = v1;
  } else {
    // final linear over vocab: g = relu(acc+bias) -> fp16 G table (8B stores)
    (void)Out;
#pragma unroll
    for (int i = 0; i < 4; ++i) {
      const size_t row = t0 + wrow * 64 + i * 16 + m_;
#pragma unroll
      for (int j = 0; j < 4; ++j) {
        union { _Float16 h[4]; unsigned long long u; } P;
#pragma unroll
        for (int r2 = 0; r2 < 4; ++r2)
          P.h[r2] = (_Float16)fmaxf(acc[i][j][r2] + bq[j][r2], 0.0f);
        *(unsigned long long*)(Of + row * 512 + (size_t)(n0 + wcol * 64 + j * 16 + qf * 4)) = P.u;
      }
    }
  }
}

// ---------------- gather: out[t][:] = (f32) G[ids[t]][:] -------------------
// 4 tokens/block, 64 threads/token, 8 halfs/thread. Reads contiguous 1KB
// L3-hot rows; writes fully-coalesced 134MB f32.
__global__ __launch_bounds__(256) void gather_kernel(
    const _Float16* __restrict__ G, const int* __restrict__ ids,
    float* __restrict__ Out)
{
  const int T = threadIdx.x;
  const int tok = blockIdx.x * 4 + (T >> 6);
  const int e = (T & 63) * 8;
  const size_t row = (size_t)(unsigned)ids[tok];
  half8 v = *(const half8*)(G + row * 512 + e);
  float4v f0, f1;
#pragma unroll
  for (int k = 0; k < 4; ++k) { f0[k] = (float)v[k]; f1[k] = (float)v[4 + k]; }
  float* d = Out + (size_t)tok * 512 + e;
  *(float4v*)d = f0;
  *(float4v*)(d + 4) = f1;
}

extern "C" void kernel_launch(void* const* d_in, const int* in_sizes, int n_in,
                              void* d_out, int out_size, void* d_ws, size_t ws_size,
                              hipStream_t stream) {
  (void)in_sizes; (void)n_in; (void)out_size; (void)ws_size;
  const int*   ids   = (const int*)d_in[0];
  const float* emb   = (const float*)d_in[1];
  const float* W0    = (const float*)d_in[2];
  // d_in[3] = W_hh0 unused (h_prev = 0)
  const float* bi0   = (const float*)d_in[4];
  const float* bh0   = (const float*)d_in[5];
  const float* W1    = (const float*)d_in[6];
  // d_in[7] = W_hh1 unused
  const float* bi1   = (const float*)d_in[8];
  const float* bh1   = (const float*)d_in[9];
  const float* WL    = (const float*)d_in[10];
  const float* blin  = (const float*)d_in[11];
  float* out = (float*)d_out;

  char* ws = (char*)d_ws;
  const size_t MB = 1024 * 1024;
  _Float16* W0f = (_Float16*)(ws);                  // 2 MB
  _Float16* W1f = (_Float16*)(ws + 2 * MB);         // 2 MB
  _Float16* WLf = (_Float16*)(ws + 4 * MB);         // 0.5 MB
  float*    b0p = (float*)(ws + 4 * MB + 512 * 1024);
  float*    b1p = (float*)(ws + 4 * MB + 512 * 1024 + 8192);
  _Float16* Ef  = (_Float16*)(ws + 8 * MB);         // vocab table 51.7MB (64MB slot)
  _Float16* H1f = Ef;                               // Ef dead after layer 0
  _Float16* H0f = (_Float16*)(ws + 72 * MB);        // 64 MB slot
  _Float16* Gf  = H0f;                              // H0f dead after layer 1
  // total ws use: 136 MB

  // Full vocab-domain pipeline (50432 padded rows, no gather in any GEMM);
  // final stage is a pure gather-copy out[t] = (f32)G[ids[t]].
  prep_kernel<<<13776, 256, 0, stream>>>(emb, W0, bi0, bh0, W1, bi1, bh1, WL,
                                         Ef, W0f, W1f, WLf, b0p, b1p);
  gemm_kernel<0><<<3152, 512, 0, stream>>>(Ef, nullptr, W0f, b0p, H0f, nullptr, 4, 15);
  gemm_kernel<0><<<3152, 512, 0, stream>>>(H0f, nullptr, W1f, b1p, H1f, nullptr, 4, 15);
  gemm_kernel<1><<<788, 512, 0, stream>>>(H1f, nullptr, WLf, blin, Gf, nullptr, 2, 3);
  gather_kernel<<<16384, 256, 0, stream>>>(Gf, ids, out);
}